// Round 4
// baseline (348.097 us; speedup 1.0000x reference)
//
#include <hip/hip_runtime.h>
#include <hip/hip_bf16.h>

#define B 16
#define L 64
#define P 1024
#define V 64
#define Q 16
#define LN64 4.158883083359672f

#define CHU 32            // p per k_uhat block
#define NCH_U (P / CHU)   // 32
#define CHBC 16           // p per k_bc block
#define NCH_BC (P / CHBC) // 64

typedef unsigned short ushort8_t __attribute__((ext_vector_type(8)));

static __device__ __forceinline__ float bf2f(ushort u) {
    return __uint_as_float(((unsigned int)u) << 16);
}
static __device__ __forceinline__ ushort f2bf(float f) {
    unsigned int x = __float_as_uint(f);
    unsigned int r = (x + 0x7fffu + ((x >> 16) & 1u)) >> 16;
    return (ushort)r;
}

static __device__ __forceinline__ float wsum64(float v) {
#pragma unroll
    for (int m = 32; m > 0; m >>= 1) v += __shfl_xor(v, m, 64);
    return v;
}
static __device__ __forceinline__ float wmax64(float v) {
#pragma unroll
    for (int m = 32; m > 0; m >>= 1) v = fmaxf(v, __shfl_xor(v, m, 64));
    return v;
}

// ---------------------------------------------------------------------------
// K_uhat v3: block = (ch, l); 32 consecutive p per block. W stream is 256 KB
// contiguous. uhat layout [l][p][b][v] -> block writes ONE contiguous 64 KB
// region. Also accumulates iter-0 partial s0 (uniform c) in registers.
// Wave w owns b in [4w,4w+4), lane = v. x chunk staged in LDS (broadcast).
// ---------------------------------------------------------------------------
__global__ __launch_bounds__(256) void k_uhat(const float* __restrict__ Wt,
                                              const float* __restrict__ x,
                                              ushort* __restrict__ uhat,
                                              float* __restrict__ sp0) {
    const int ch = blockIdx.x, l = blockIdx.y;
    const int p0 = ch * CHU;
    const int t = threadIdx.x;
    const int w = t >> 6;
    const int lane = t & 63;   // v
    const int b0 = w * 4;

    __shared__ float xs[CHU][B][Q];   // 32 KB, [pp][b][q]
#pragma unroll
    for (int i = 0; i < 32; ++i) {
        int f = t + i * 256;              // b major, then pp, then q
        int b = f >> 9, rem = f & 511;
        int pp = rem >> 4, q = rem & 15;
        xs[pp][b][q] = x[((size_t)b * P + p0 + pp) * Q + q];
    }
    __syncthreads();

    float acc[4] = {0.f, 0.f, 0.f, 0.f};   // s0 partial for (b0+i, v=lane)

    const float4* Wp0 = reinterpret_cast<const float4*>(Wt) +
                        (((size_t)l * P + p0) * V + lane) * 4;
    ushort* ub = uhat + (((size_t)l * P + p0) * B) * V + lane;

    float4 Wa[4], Wb[4];
#define LOADW(pp, d)                                                          \
    {                                                                         \
        const float4* wp = Wp0 + (size_t)(pp) * (V * 4);                      \
        d[0] = wp[0]; d[1] = wp[1]; d[2] = wp[2]; d[3] = wp[3];               \
    }
#define COMPUTE(pp, Wr)                                                       \
    {                                                                         \
        _Pragma("unroll")                                                     \
        for (int i = 0; i < 4; ++i) {                                         \
            float4 xa = *reinterpret_cast<const float4*>(&xs[pp][b0 + i][0]); \
            float4 xb = *reinterpret_cast<const float4*>(&xs[pp][b0 + i][4]); \
            float4 xc = *reinterpret_cast<const float4*>(&xs[pp][b0 + i][8]); \
            float4 xd = *reinterpret_cast<const float4*>(&xs[pp][b0 + i][12]);\
            float u = 0.f;                                                    \
            u = fmaf(Wr[0].x, xa.x, u); u = fmaf(Wr[0].y, xa.y, u);           \
            u = fmaf(Wr[0].z, xa.z, u); u = fmaf(Wr[0].w, xa.w, u);           \
            u = fmaf(Wr[1].x, xb.x, u); u = fmaf(Wr[1].y, xb.y, u);           \
            u = fmaf(Wr[1].z, xb.z, u); u = fmaf(Wr[1].w, xb.w, u);           \
            u = fmaf(Wr[2].x, xc.x, u); u = fmaf(Wr[2].y, xc.y, u);           \
            u = fmaf(Wr[2].z, xc.z, u); u = fmaf(Wr[2].w, xc.w, u);           \
            u = fmaf(Wr[3].x, xd.x, u); u = fmaf(Wr[3].y, xd.y, u);           \
            u = fmaf(Wr[3].z, xd.z, u); u = fmaf(Wr[3].w, xd.w, u);           \
            ushort ur = f2bf(u);                                              \
            ub[((size_t)(pp) * B + b0 + i) * V] = ur;                         \
            acc[i] += bf2f(ur);                                               \
        }                                                                     \
    }

    LOADW(0, Wa);
#pragma unroll 2
    for (int pp = 0; pp < CHU; pp += 2) {
        LOADW(pp + 1, Wb);
        COMPUTE(pp, Wa);
        if (pp + 2 < CHU) LOADW(pp + 2, Wa);
        COMPUTE(pp + 1, Wb);
    }
#undef LOADW
#undef COMPUTE

    // sp0[l][ch][b][v] ; uniform c = 1/64 applied here
#pragma unroll
    for (int i = 0; i < 4; ++i)
        sp0[(((size_t)l * NCH_U + ch) * B + b0 + i) * V + lane] = acc[i] * (1.0f / 64.0f);
}

// ---------------------------------------------------------------------------
// K_v: generic chunk-reduce + squash. idx(src) = cb*b + cl*l + cs*ch + v.
// grid (L/4, B), 256 threads; wave w -> l = bx*4 + w, lane = v.
// ---------------------------------------------------------------------------
__global__ __launch_bounds__(256) void k_v(const float* __restrict__ sp,
                                           int cb, int cl, int cs, int nch,
                                           float* __restrict__ vout,
                                           float* __restrict__ norms) {
    const int b = blockIdx.y;
    const int w = threadIdx.x >> 6, lane = threadIdx.x & 63;
    const int l = blockIdx.x * 4 + w;
    const float* p = sp + (size_t)cb * b + (size_t)cl * l + lane;
    float s = 0.f;
    for (int ch = 0; ch < nch; ++ch) s += p[(size_t)ch * cs];
    float sq = wsum64(s * s);
    float f = sqrtf(sq) / (1.0f + sq);
    vout[((size_t)b * L + l) * V + lane] = s * f;
    if (norms && lane == 0) norms[b * L + l] = sq / (1.0f + sq);
}

// ---------------------------------------------------------------------------
// K_bc v3: block = (ch of 16 p, b).
// phase 1: bl[p][l] = sum_v u[l,p,v]*v[l,v]  (waves split l; 8 lanes/p x ushort8)
// phase 2: softmax over l per p (wave-parallel), b-logit update, optional T.
// phase 3: partial s[l][v] = sum_{p in chunk} c[p]*u[l,p,v] (u tile L2-hot),
//          written to sp[b][ch][l][v].
// ---------------------------------------------------------------------------
__global__ __launch_bounds__(256) void k_bc(const ushort* __restrict__ uhat,
                                            const float* __restrict__ vv,
                                            float* __restrict__ bbuf,
                                            float* __restrict__ sp,
                                            float* __restrict__ Tsum,
                                            int add_prev, int do_T) {
    const int ch = blockIdx.x, b = blockIdx.y;
    const int p0 = ch * CHBC;
    const int t = threadIdx.x;
    const int w = t >> 6, lane = t & 63;
    const int pl8 = lane >> 3;   // 0..7
    const int vg8 = lane & 7;    // v-octet

    __shared__ float vsh[L][V];       // 16 KB
    __shared__ float bl[CHBC][L];     // 4 KB [p][l]
    __shared__ float ctT[L][CHBC];    // 4 KB [l][p]

    // stage v[b,:,:]
    {
        const float4* vvp = reinterpret_cast<const float4*>(vv + (size_t)b * L * V);
        float4* vshp = reinterpret_cast<float4*>(&vsh[0][0]);
#pragma unroll
        for (int i = 0; i < 4; ++i) vshp[t + i * 256] = vvp[t + i * 256];
    }
    __syncthreads();

    // phase 1: waves split l (16 each); 8 lanes per p, ushort8 per lane
#pragma unroll 4
    for (int li = 0; li < 16; ++li) {
        const int l = w * 16 + li;
        float4 va = *reinterpret_cast<const float4*>(&vsh[l][vg8 * 8]);
        float4 vb = *reinterpret_cast<const float4*>(&vsh[l][vg8 * 8 + 4]);
#pragma unroll
        for (int ph = 0; ph < 2; ++ph) {
            const int pl = ph * 8 + pl8;
            const ushort8_t u = *reinterpret_cast<const ushort8_t*>(
                uhat + (((size_t)l * P + p0 + pl) * B + b) * V + vg8 * 8);
            float d = bf2f(u[0]) * va.x + bf2f(u[1]) * va.y +
                      bf2f(u[2]) * va.z + bf2f(u[3]) * va.w +
                      bf2f(u[4]) * vb.x + bf2f(u[5]) * vb.y +
                      bf2f(u[6]) * vb.z + bf2f(u[7]) * vb.w;
            d += __shfl_xor(d, 1, 64);
            d += __shfl_xor(d, 2, 64);
            d += __shfl_xor(d, 4, 64);
            if (vg8 == 0) bl[pl][l] = d;
        }
    }
    __syncthreads();

    // phase 2: each wave softmaxes 4 p's (lane = l)
    float tloc = 0.f;
#pragma unroll
    for (int pi = 0; pi < 4; ++pi) {
        const int pli = w * 4 + pi;
        const int p = p0 + pli;
        float bv = bl[pli][lane];
        float* bp = bbuf + ((size_t)b * P + p) * L;
        if (add_prev) bv += bp[lane];
        bp[lane] = bv;
        float m = wmax64(bv);
        float e = __expf(bv - m);
        float ssum = wsum64(e);
        float cc = e / ssum;
        ctT[lane][pli] = cc;
        if (do_T) tloc += cc * __logf(64.0f * (cc + 1e-12f));
    }
    if (do_T) {
        float dsum = wsum64(tloc);
        if (lane == 0) atomicAdd(Tsum, dsum * (1.0f / LN64));
    }
    __syncthreads();

    // phase 3: partial s; waves split l (16 each), lane = v; u tile is L2-hot
#pragma unroll 2
    for (int li = 0; li < 16; ++li) {
        const int l = w * 16 + li;
        float4 c0 = *reinterpret_cast<const float4*>(&ctT[l][0]);
        float4 c1 = *reinterpret_cast<const float4*>(&ctT[l][4]);
        float4 c2 = *reinterpret_cast<const float4*>(&ctT[l][8]);
        float4 c3 = *reinterpret_cast<const float4*>(&ctT[l][12]);
        const ushort* up = uhat + (((size_t)l * P + p0) * B + b) * V + lane;
        const size_t st = (size_t)B * V;
        float s = 0.f;
        s = fmaf(c0.x, bf2f(up[0 * st]), s);
        s = fmaf(c0.y, bf2f(up[1 * st]), s);
        s = fmaf(c0.z, bf2f(up[2 * st]), s);
        s = fmaf(c0.w, bf2f(up[3 * st]), s);
        s = fmaf(c1.x, bf2f(up[4 * st]), s);
        s = fmaf(c1.y, bf2f(up[5 * st]), s);
        s = fmaf(c1.z, bf2f(up[6 * st]), s);
        s = fmaf(c1.w, bf2f(up[7 * st]), s);
        s = fmaf(c2.x, bf2f(up[8 * st]), s);
        s = fmaf(c2.y, bf2f(up[9 * st]), s);
        s = fmaf(c2.z, bf2f(up[10 * st]), s);
        s = fmaf(c2.w, bf2f(up[11 * st]), s);
        s = fmaf(c3.x, bf2f(up[12 * st]), s);
        s = fmaf(c3.y, bf2f(up[13 * st]), s);
        s = fmaf(c3.z, bf2f(up[14 * st]), s);
        s = fmaf(c3.w, bf2f(up[15 * st]), s);
        sp[(((size_t)b * NCH_BC + ch) * L + l) * V + lane] = s;
    }
}

// ---------------------------------------------------------------------------
// K_final: T and D. One block, 64 threads (lane = l).
// ---------------------------------------------------------------------------
__global__ void k_final(const float* __restrict__ Tsum,
                        const float* __restrict__ norms,
                        float* __restrict__ out) {
    const int lane = threadIdx.x & 63;
    float n[B];
    float sum = 0.f;
#pragma unroll
    for (int b = 0; b < B; ++b) { n[b] = norms[b * L + lane]; sum += n[b]; }
    const float mean = sum * (1.0f / B);
    float var = 0.f;
#pragma unroll
    for (int b = 0; b < B; ++b) { float d = n[b] - mean; var = fmaf(d, d, var); }
    var *= (1.0f / B);
    float sd = sqrtf(var);
    float D = wmax64(sd);
    if (lane == 0) {
        out[B * L * V] = Tsum[0] * (1.0f / (B * P));
        out[B * L * V + 1] = D;
    }
}

extern "C" void kernel_launch(void* const* d_in, const int* in_sizes, int n_in,
                              void* d_out, int out_size, void* d_ws, size_t ws_size,
                              hipStream_t stream) {
    const float* x = (const float*)d_in[0];   // (B,P,Q)
    const float* W = (const float*)d_in[1];   // (L,P,V,Q)
    float* out = (float*)d_out;               // v (B,L,V) then T, D

    char* ws = (char*)d_ws;
    ushort* uhat = (ushort*)ws;                        // [l][p][b][v] bf16 = 128 MB
    size_t off = (size_t)L * P * B * V * 2;
    float* spbuf = (float*)(ws + off); off += (size_t)B * NCH_BC * L * V * 4;  // 16 MB (sp0 & sp share)
    float* vbuf  = (float*)(ws + off); off += (size_t)B * L * V * 4;
    float* bbuf  = (float*)(ws + off); off += (size_t)B * P * L * 4;           // 4 MB [b][p][l]
    float* norms = (float*)(ws + off); off += (size_t)B * L * 4;
    float* Tsum  = (float*)(ws + off); off += 256;

    hipMemsetAsync(Tsum, 0, sizeof(float), stream);

    // u_hat + iter-0 partial s0 (sp0[l][ch][b][v], NCH_U chunks)
    hipLaunchKernelGGL(k_uhat, dim3(NCH_U, L), dim3(256), 0, stream, W, x, uhat, spbuf);
    // v0 = squash(reduce sp0)
    hipLaunchKernelGGL(k_v, dim3(L / 4, B), dim3(256), 0, stream,
                       spbuf, V, NCH_U * B * V, B * V, NCH_U, vbuf, (float*)nullptr);
    // b1 = v0.u ; c1 ; partial s1 -> sp[b][ch][l][v]
    hipLaunchKernelGGL(k_bc, dim3(NCH_BC, B), dim3(256), 0, stream,
                       uhat, vbuf, bbuf, spbuf, Tsum, 0, 0);
    // v1
    hipLaunchKernelGGL(k_v, dim3(L / 4, B), dim3(256), 0, stream,
                       spbuf, NCH_BC * L * V, V, L * V, NCH_BC, vbuf, (float*)nullptr);
    // b2 = b1 + v1.u ; c2 ; T partials ; partial s2
    hipLaunchKernelGGL(k_bc, dim3(NCH_BC, B), dim3(256), 0, stream,
                       uhat, vbuf, bbuf, spbuf, Tsum, 1, 1);
    // v2 -> out, norms
    hipLaunchKernelGGL(k_v, dim3(L / 4, B), dim3(256), 0, stream,
                       spbuf, NCH_BC * L * V, V, L * V, NCH_BC, out, norms);
    hipLaunchKernelGGL(k_final, dim3(1), dim3(64), 0, stream, Tsum, norms, out);
}

// Round 5
// 328.503 us; speedup vs baseline: 1.0596x; 1.0596x over previous
//
#include <hip/hip_runtime.h>
#include <hip/hip_bf16.h>

#define B 16
#define L 64
#define P 1024
#define V 64
#define Q 16
#define LN64 4.158883083359672f

#define CHBC 16           // p per k_bc block
#define NCH_BC (P / CHBC) // 64

typedef unsigned short ushort8_t __attribute__((ext_vector_type(8)));

static __device__ __forceinline__ float bf2f(ushort u) {
    return __uint_as_float(((unsigned int)u) << 16);
}
static __device__ __forceinline__ ushort f2bf(float f) {
    unsigned int x = __float_as_uint(f);
    unsigned int r = (x + 0x7fffu + ((x >> 16) & 1u)) >> 16;
    return (ushort)r;
}

static __device__ __forceinline__ float wsum64(float v) {
#pragma unroll
    for (int m = 32; m > 0; m >>= 1) v += __shfl_xor(v, m, 64);
    return v;
}
static __device__ __forceinline__ float wmax64(float v) {
#pragma unroll
    for (int m = 32; m > 0; m >>= 1) v = fmaxf(v, __shfl_xor(v, m, 64));
    return v;
}

// ---------------------------------------------------------------------------
// K_uhat v4: block = (p, l-half). 4 waves; wave w owns b in [4w,4w+4), lane=v.
// x[:,p,:] staged through LDS into 64 regs/thread. W loads 4-deep pipelined
// (covers ~680 cyc of HBM latency at 3-4 waves/SIMD). uhat layout [b][l][p][v].
// ---------------------------------------------------------------------------
__global__ __launch_bounds__(256) void k_uhat(const float* __restrict__ Wt,
                                              const float* __restrict__ x,
                                              ushort* __restrict__ uhat) {
    const int t = threadIdx.x;
    const int w = t >> 6;          // b-group
    const int lane = t & 63;       // v
    const int p = blockIdx.x >> 1;
    const int l0 = (blockIdx.x & 1) * 32;

    __shared__ float xs[B * Q];    // 1 KB
    {
        const int b = t >> 4, q = t & 15;
        xs[t] = x[((size_t)b * P + p) * Q + q];
    }
    __syncthreads();

    float xr[4][Q];                // wave's 4 b rows of x
#pragma unroll
    for (int i = 0; i < 4; ++i)
#pragma unroll
        for (int q = 0; q < Q; ++q) xr[i][q] = xs[(w * 4 + i) * Q + q];

    const float4* Wp0 = reinterpret_cast<const float4*>(Wt);

    float4 Wb[4][4];               // 4-deep pipeline
#define LOADW(l, d)                                                          \
    {                                                                        \
        const float4* wp = Wp0 + (((size_t)(l) * P + p) * V + lane) * 4;     \
        d[0] = wp[0]; d[1] = wp[1]; d[2] = wp[2]; d[3] = wp[3];              \
    }
#define COMPUTE(l, Wr)                                                       \
    {                                                                        \
        _Pragma("unroll")                                                    \
        for (int i = 0; i < 4; ++i) {                                        \
            float u = 0.f;                                                   \
            _Pragma("unroll")                                                \
            for (int q4 = 0; q4 < 4; ++q4) {                                 \
                u = fmaf(Wr[q4].x, xr[i][q4 * 4 + 0], u);                    \
                u = fmaf(Wr[q4].y, xr[i][q4 * 4 + 1], u);                    \
                u = fmaf(Wr[q4].z, xr[i][q4 * 4 + 2], u);                    \
                u = fmaf(Wr[q4].w, xr[i][q4 * 4 + 3], u);                    \
            }                                                                \
            const int b = w * 4 + i;                                         \
            uhat[(((size_t)(b * L + (l))) * P + p) * V + lane] = f2bf(u);    \
        }                                                                    \
    }

    LOADW(l0 + 0, Wb[0]);
    LOADW(l0 + 1, Wb[1]);
    LOADW(l0 + 2, Wb[2]);
    LOADW(l0 + 3, Wb[3]);
#pragma unroll
    for (int li = 0; li < 32; ++li) {
        COMPUTE(l0 + li, Wb[li & 3]);
        if (li + 4 < 32) LOADW(l0 + li + 4, Wb[li & 3]);
    }
#undef LOADW
#undef COMPUTE
}

// ---------------------------------------------------------------------------
// K_s: per (b,l) block, iter-0 only (uniform c). s[v] = (1/64) sum_p u[p,v],
// fused squash. Thread t owns (pl = t>>4, v0 = (t&15)*4); ushort4 loads.
// ---------------------------------------------------------------------------
__global__ __launch_bounds__(256) void k_s(const ushort* __restrict__ uhat,
                                           float* __restrict__ vout) {
    const int l = blockIdx.x, b = blockIdx.y;
    const int t = threadIdx.x;
    const int w = t >> 6, lane = t & 63;
    const int pl = t >> 4;      // 0..15
    const int vg = t & 15;      // v0 = vg*4

    __shared__ float4 sl[4][16];

    const ushort* up = uhat + ((size_t)(b * L + l)) * P * V + (size_t)pl * V + vg * 4;

    float4 acc = {0.f, 0.f, 0.f, 0.f};
#pragma unroll 8
    for (int i = 0; i < 64; ++i) {
        ushort4 u = *reinterpret_cast<const ushort4*>(up + (size_t)i * 16 * V);
        acc.x += bf2f(u.x); acc.y += bf2f(u.y);
        acc.z += bf2f(u.z); acc.w += bf2f(u.w);
    }
    acc.x *= (1.f / 64.f); acc.y *= (1.f / 64.f);
    acc.z *= (1.f / 64.f); acc.w *= (1.f / 64.f);
#pragma unroll
    for (int m = 16; m <= 32; m <<= 1) {
        acc.x += __shfl_xor(acc.x, m, 64);
        acc.y += __shfl_xor(acc.y, m, 64);
        acc.z += __shfl_xor(acc.z, m, 64);
        acc.w += __shfl_xor(acc.w, m, 64);
    }
    if (lane < 16) sl[w][vg] = acc;
    __syncthreads();
    if (w == 0 && lane < 16) {
        float4 s0 = sl[0][vg], s1 = sl[1][vg], s2 = sl[2][vg], s3 = sl[3][vg];
        float4 s;
        s.x = s0.x + s1.x + s2.x + s3.x;
        s.y = s0.y + s1.y + s2.y + s3.y;
        s.z = s0.z + s1.z + s2.z + s3.z;
        s.w = s0.w + s1.w + s2.w + s3.w;
        float sq = s.x * s.x + s.y * s.y + s.z * s.z + s.w * s.w;
        sq += __shfl_xor(sq, 1, 64);
        sq += __shfl_xor(sq, 2, 64);
        sq += __shfl_xor(sq, 4, 64);
        sq += __shfl_xor(sq, 8, 64);
        float f = sqrtf(sq) / (1.0f + sq);
        float4 o = {s.x * f, s.y * f, s.z * f, s.w * f};
        *reinterpret_cast<float4*>(vout + (size_t)(b * L + l) * V + vg * 4) = o;
    }
}

// ---------------------------------------------------------------------------
// K_bc v5: block = (ch of 16 p, b), 512 threads (8 waves), 1 block/CU.
// phase 1: stream u tile (128 KB) from HBM -> LDS, fused dot with v -> bl[p][l]
// phase 2: softmax over l per p (each wave 2 p's); b-logit update; optional T;
//          c overwrites bl in place.
// phase 3: partial s[l][v] = sum_p c[p]*u[l,p,v] from LDS -> sp[b][ch][l][v].
// u_hat crosses HBM exactly once per launch.
// ---------------------------------------------------------------------------
__global__ __launch_bounds__(512) void k_bc(const ushort* __restrict__ uhat,
                                            const float* __restrict__ vv,
                                            float* __restrict__ bbuf,
                                            float* __restrict__ sp,
                                            float* __restrict__ Tsum,
                                            int add_prev, int do_T) {
    const int ch = blockIdx.x, b = blockIdx.y;
    const int p0 = ch * CHBC;
    const int t = threadIdx.x;
    const int w = t >> 6, lane = t & 63;
    const int pl8 = lane >> 3;   // 0..7
    const int vg8 = lane & 7;    // v-octet

    __shared__ ushort uls[L][CHBC][V];  // 128 KB
    __shared__ float vsh[L][V];         // 16 KB
    __shared__ float bl[CHBC][L];       // 4 KB  (logits, then c in place)

    // stage v[b,:,:]
    {
        const float4* vvp = reinterpret_cast<const float4*>(vv + (size_t)b * L * V);
        float4* vshp = reinterpret_cast<float4*>(&vsh[0][0]);
#pragma unroll
        for (int i = 0; i < 2; ++i) vshp[t + i * 512] = vvp[t + i * 512];
    }
    __syncthreads();

    // phase 1: each wave streams 8 l's; per l two 1KB-contiguous ushort8 loads
#pragma unroll 4
    for (int li = 0; li < 8; ++li) {
        const int l = w * 8 + li;
        float4 va = *reinterpret_cast<const float4*>(&vsh[l][vg8 * 8]);
        float4 vb = *reinterpret_cast<const float4*>(&vsh[l][vg8 * 8 + 4]);
#pragma unroll
        for (int ph = 0; ph < 2; ++ph) {
            const int pl = ph * 8 + pl8;
            const ushort8_t u = *reinterpret_cast<const ushort8_t*>(
                uhat + (((size_t)(b * L + l)) * P + p0 + pl) * V + vg8 * 8);
            *reinterpret_cast<ushort8_t*>(&uls[l][pl][vg8 * 8]) = u;
            float d = bf2f(u[0]) * va.x + bf2f(u[1]) * va.y +
                      bf2f(u[2]) * va.z + bf2f(u[3]) * va.w +
                      bf2f(u[4]) * vb.x + bf2f(u[5]) * vb.y +
                      bf2f(u[6]) * vb.z + bf2f(u[7]) * vb.w;
            d += __shfl_xor(d, 1, 64);
            d += __shfl_xor(d, 2, 64);
            d += __shfl_xor(d, 4, 64);
            if (vg8 == 0) bl[pl][l] = d;
        }
    }
    __syncthreads();

    // phase 2: each wave softmaxes 2 p's (lane = l); c overwrites bl
    float tloc = 0.f;
#pragma unroll
    for (int pi = 0; pi < 2; ++pi) {
        const int pli = w * 2 + pi;
        const int p = p0 + pli;
        float bv = bl[pli][lane];
        float* bp = bbuf + ((size_t)b * P + p) * L;
        if (add_prev) bv += bp[lane];
        bp[lane] = bv;
        float m = wmax64(bv);
        float e = __expf(bv - m);
        float ssum = wsum64(e);
        float cc = e / ssum;
        bl[pli][lane] = cc;
        if (do_T) tloc += cc * __logf(64.0f * (cc + 1e-12f));
    }
    if (do_T) {
        float dsum = wsum64(tloc);
        if (lane == 0) atomicAdd(Tsum, dsum * (1.0f / LN64));
    }
    __syncthreads();

    // phase 3: partial s from LDS; wave w -> 8 l's, lane = v; c broadcast
#pragma unroll 2
    for (int li = 0; li < 8; ++li) {
        const int l = w * 8 + li;
        float s = 0.f;
#pragma unroll
        for (int pp = 0; pp < CHBC; ++pp) {
            s = fmaf(bl[pp][l], bf2f(uls[l][pp][lane]), s);
        }
        sp[(((size_t)b * NCH_BC + ch) * L + l) * V + lane] = s;
    }
}

// ---------------------------------------------------------------------------
// K_v: chunk-reduce + squash. sp[b][ch][l][v]. grid (L/4, B); wave w -> l.
// ---------------------------------------------------------------------------
__global__ __launch_bounds__(256) void k_v(const float* __restrict__ sp,
                                           float* __restrict__ vout,
                                           float* __restrict__ norms) {
    const int b = blockIdx.y;
    const int w = threadIdx.x >> 6, lane = threadIdx.x & 63;
    const int l = blockIdx.x * 4 + w;
    const float* p = sp + ((size_t)b * NCH_BC * L + l) * V + lane;
    float s = 0.f;
#pragma unroll 8
    for (int ch = 0; ch < NCH_BC; ++ch) s += p[(size_t)ch * L * V];
    float sq = wsum64(s * s);
    float f = sqrtf(sq) / (1.0f + sq);
    vout[((size_t)b * L + l) * V + lane] = s * f;
    if (norms && lane == 0) norms[b * L + l] = sq / (1.0f + sq);
}

// ---------------------------------------------------------------------------
// K_final: T and D. One block, 64 threads (lane = l).
// ---------------------------------------------------------------------------
__global__ void k_final(const float* __restrict__ Tsum,
                        const float* __restrict__ norms,
                        float* __restrict__ out) {
    const int lane = threadIdx.x & 63;
    float n[B];
    float sum = 0.f;
#pragma unroll
    for (int b = 0; b < B; ++b) { n[b] = norms[b * L + lane]; sum += n[b]; }
    const float mean = sum * (1.0f / B);
    float var = 0.f;
#pragma unroll
    for (int b = 0; b < B; ++b) { float d = n[b] - mean; var = fmaf(d, d, var); }
    var *= (1.0f / B);
    float sd = sqrtf(var);
    float D = wmax64(sd);
    if (lane == 0) {
        out[B * L * V] = Tsum[0] * (1.0f / (B * P));
        out[B * L * V + 1] = D;
    }
}

extern "C" void kernel_launch(void* const* d_in, const int* in_sizes, int n_in,
                              void* d_out, int out_size, void* d_ws, size_t ws_size,
                              hipStream_t stream) {
    const float* x = (const float*)d_in[0];   // (B,P,Q)
    const float* W = (const float*)d_in[1];   // (L,P,V,Q)
    float* out = (float*)d_out;               // v (B,L,V) then T, D

    char* ws = (char*)d_ws;
    ushort* uhat = (ushort*)ws;                        // [b][l][p][v] bf16 = 128 MB
    size_t off = (size_t)B * L * P * V * 2;
    float* spbuf = (float*)(ws + off); off += (size_t)B * NCH_BC * L * V * 4;  // 16 MB
    float* vbuf  = (float*)(ws + off); off += (size_t)B * L * V * 4;
    float* bbuf  = (float*)(ws + off); off += (size_t)B * P * L * 4;           // 4 MB [b][p][l]
    float* norms = (float*)(ws + off); off += (size_t)B * L * 4;
    float* Tsum  = (float*)(ws + off); off += 256;

    hipMemsetAsync(Tsum, 0, sizeof(float), stream);

    // u_hat
    hipLaunchKernelGGL(k_uhat, dim3(2048), dim3(256), 0, stream, W, x, uhat);
    // iter 0: uniform c -> v0
    hipLaunchKernelGGL(k_s, dim3(L, B), dim3(256), 0, stream, uhat, vbuf);
    // b1 = v0.u ; c1 ; partial s1 (fused, u via LDS)
    hipLaunchKernelGGL(k_bc, dim3(NCH_BC, B), dim3(512), 0, stream,
                       uhat, vbuf, bbuf, spbuf, Tsum, 0, 0);
    // v1
    hipLaunchKernelGGL(k_v, dim3(L / 4, B), dim3(256), 0, stream,
                       spbuf, vbuf, (float*)nullptr);
    // b2 = b1 + v1.u ; c2 ; T partials ; partial s2
    hipLaunchKernelGGL(k_bc, dim3(NCH_BC, B), dim3(512), 0, stream,
                       uhat, vbuf, bbuf, spbuf, Tsum, 1, 1);
    // v2 -> out, norms
    hipLaunchKernelGGL(k_v, dim3(L / 4, B), dim3(256), 0, stream,
                       spbuf, out, norms);
    hipLaunchKernelGGL(k_final, dim3(1), dim3(64), 0, stream, Tsum, norms, out);
}

// Round 6
// 251.644 us; speedup vs baseline: 1.3833x; 1.3054x over previous
//
#include <hip/hip_runtime.h>
#include <hip/hip_bf16.h>

#define B 16
#define L 64
#define P 1024
#define V 64
#define Q 16
#define LN64 4.158883083359672f

#define CHBC 16           // p per k_bc block
#define NCH_BC (P / CHBC) // 64

typedef unsigned short ushort8_t __attribute__((ext_vector_type(8)));

static __device__ __forceinline__ float bf2f(ushort u) {
    return __uint_as_float(((unsigned int)u) << 16);
}
static __device__ __forceinline__ ushort f2bf(float f) {
    unsigned int x = __float_as_uint(f);
    unsigned int r = (x + 0x7fffu + ((x >> 16) & 1u)) >> 16;
    return (ushort)r;
}

static __device__ __forceinline__ float wsum64(float v) {
#pragma unroll
    for (int m = 32; m > 0; m >>= 1) v += __shfl_xor(v, m, 64);
    return v;
}
static __device__ __forceinline__ float wmax64(float v) {
#pragma unroll
    for (int m = 32; m > 0; m >>= 1) v = fmaxf(v, __shfl_xor(v, m, 64));
    return v;
}

// ---------------------------------------------------------------------------
// K_uhat v4: block = (p, l-half). 4 waves; wave w owns b in [4w,4w+4), lane=v.
// x[:,p,:] staged through LDS into 64 regs/thread. W loads 4-deep pipelined.
// uhat layout [b][l][p][v].
// ---------------------------------------------------------------------------
__global__ __launch_bounds__(256) void k_uhat(const float* __restrict__ Wt,
                                              const float* __restrict__ x,
                                              ushort* __restrict__ uhat) {
    const int t = threadIdx.x;
    const int w = t >> 6;          // b-group
    const int lane = t & 63;       // v
    const int p = blockIdx.x >> 1;
    const int l0 = (blockIdx.x & 1) * 32;

    __shared__ float xs[B * Q];    // 1 KB
    {
        const int b = t >> 4, q = t & 15;
        xs[t] = x[((size_t)b * P + p) * Q + q];
    }
    __syncthreads();

    float xr[4][Q];                // wave's 4 b rows of x
#pragma unroll
    for (int i = 0; i < 4; ++i)
#pragma unroll
        for (int q = 0; q < Q; ++q) xr[i][q] = xs[(w * 4 + i) * Q + q];

    const float4* Wp0 = reinterpret_cast<const float4*>(Wt);

    float4 Wb[4][4];               // 4-deep pipeline
#define LOADW(l, d)                                                          \
    {                                                                        \
        const float4* wp = Wp0 + (((size_t)(l) * P + p) * V + lane) * 4;     \
        d[0] = wp[0]; d[1] = wp[1]; d[2] = wp[2]; d[3] = wp[3];              \
    }
#define COMPUTE(l, Wr)                                                       \
    {                                                                        \
        _Pragma("unroll")                                                    \
        for (int i = 0; i < 4; ++i) {                                        \
            float u = 0.f;                                                   \
            _Pragma("unroll")                                                \
            for (int q4 = 0; q4 < 4; ++q4) {                                 \
                u = fmaf(Wr[q4].x, xr[i][q4 * 4 + 0], u);                    \
                u = fmaf(Wr[q4].y, xr[i][q4 * 4 + 1], u);                    \
                u = fmaf(Wr[q4].z, xr[i][q4 * 4 + 2], u);                    \
                u = fmaf(Wr[q4].w, xr[i][q4 * 4 + 3], u);                    \
            }                                                                \
            const int b = w * 4 + i;                                         \
            uhat[(((size_t)(b * L + (l))) * P + p) * V + lane] = f2bf(u);    \
        }                                                                    \
    }

    LOADW(l0 + 0, Wb[0]);
    LOADW(l0 + 1, Wb[1]);
    LOADW(l0 + 2, Wb[2]);
    LOADW(l0 + 3, Wb[3]);
#pragma unroll
    for (int li = 0; li < 32; ++li) {
        COMPUTE(l0 + li, Wb[li & 3]);
        if (li + 4 < 32) LOADW(l0 + li + 4, Wb[li & 3]);
    }
#undef LOADW
#undef COMPUTE
}

// ---------------------------------------------------------------------------
// K_s: per (b,l) block, iter-0 only (uniform c). s[v] = (1/64) sum_p u[p,v],
// fused squash. Thread t owns (pl = t>>4, v0 = (t&15)*4); ushort4 loads.
// ---------------------------------------------------------------------------
__global__ __launch_bounds__(256) void k_s(const ushort* __restrict__ uhat,
                                           float* __restrict__ vout) {
    const int l = blockIdx.x, b = blockIdx.y;
    const int t = threadIdx.x;
    const int w = t >> 6, lane = t & 63;
    const int pl = t >> 4;      // 0..15
    const int vg = t & 15;      // v0 = vg*4

    __shared__ float4 sl[4][16];

    const ushort* up = uhat + ((size_t)(b * L + l)) * P * V + (size_t)pl * V + vg * 4;

    float4 acc = {0.f, 0.f, 0.f, 0.f};
#pragma unroll 8
    for (int i = 0; i < 64; ++i) {
        ushort4 u = *reinterpret_cast<const ushort4*>(up + (size_t)i * 16 * V);
        acc.x += bf2f(u.x); acc.y += bf2f(u.y);
        acc.z += bf2f(u.z); acc.w += bf2f(u.w);
    }
    acc.x *= (1.f / 64.f); acc.y *= (1.f / 64.f);
    acc.z *= (1.f / 64.f); acc.w *= (1.f / 64.f);
#pragma unroll
    for (int m = 16; m <= 32; m <<= 1) {
        acc.x += __shfl_xor(acc.x, m, 64);
        acc.y += __shfl_xor(acc.y, m, 64);
        acc.z += __shfl_xor(acc.z, m, 64);
        acc.w += __shfl_xor(acc.w, m, 64);
    }
    if (lane < 16) sl[w][vg] = acc;
    __syncthreads();
    if (w == 0 && lane < 16) {
        float4 s0 = sl[0][vg], s1 = sl[1][vg], s2 = sl[2][vg], s3 = sl[3][vg];
        float4 s;
        s.x = s0.x + s1.x + s2.x + s3.x;
        s.y = s0.y + s1.y + s2.y + s3.y;
        s.z = s0.z + s1.z + s2.z + s3.z;
        s.w = s0.w + s1.w + s2.w + s3.w;
        float sq = s.x * s.x + s.y * s.y + s.z * s.z + s.w * s.w;
        sq += __shfl_xor(sq, 1, 64);
        sq += __shfl_xor(sq, 2, 64);
        sq += __shfl_xor(sq, 4, 64);
        sq += __shfl_xor(sq, 8, 64);
        float f = sqrtf(sq) / (1.0f + sq);
        float4 o = {s.x * f, s.y * f, s.z * f, s.w * f};
        *reinterpret_cast<float4*>(vout + (size_t)(b * L + l) * V + vg * 4) = o;
    }
}

// ---------------------------------------------------------------------------
// K_bc v6: block = (ch of 16 p, b), 512 threads (8 waves). u tile kept in
// REGISTERS (ur[8][2] ushort8 per thread = 64 VGPR); LDS only vsh+bl (20 KB)
// -> 2 blocks/CU. lane = (pl8 = p, vg8 = v-octet); wave w owns l in [8w,8w+8).
// phase 1: issue all 16 coalesced 1KB u-loads, dot with v -> bl[p][l].
// phase 2: softmax over l per p (each wave 2 p's); b-logit update; optional T.
// phase 3: s-partial from registers, butterfly over pl8 -> sp[b][ch][l][v].
// u_hat crosses HBM exactly once per launch.
// ---------------------------------------------------------------------------
__global__ __launch_bounds__(512, 4) void k_bc(const ushort* __restrict__ uhat,
                                               const float* __restrict__ vv,
                                               float* __restrict__ bbuf,
                                               float* __restrict__ sp,
                                               float* __restrict__ Tsum,
                                               int add_prev, int do_T) {
    const int ch = blockIdx.x, b = blockIdx.y;
    const int p0 = ch * CHBC;
    const int t = threadIdx.x;
    const int w = t >> 6, lane = t & 63;
    const int pl8 = lane >> 3;   // p-local (phase 0 of 8)
    const int vg8 = lane & 7;    // v-octet
    const int l0 = w * 8;

    __shared__ float vsh[L][V];         // 16 KB
    __shared__ float bl[CHBC][L + 1];   // 4.06 KB (logits, then c in place)
    __shared__ float twv[8];

    // stage v[b,:,:] (ds_writes complete at the barrier)
    {
        const float4* vvp = reinterpret_cast<const float4*>(vv + (size_t)b * L * V);
        float4* vshp = reinterpret_cast<float4*>(&vsh[0][0]);
#pragma unroll
        for (int i = 0; i < 2; ++i) vshp[t + i * 512] = vvp[t + i * 512];
    }

    // issue ALL u loads before the barrier (latency overlaps the v-stage)
    ushort8_t ur[8][2];
    {
        const ushort* ubase = uhat + (((size_t)(b * L + l0)) * P + p0 + pl8) * V + vg8 * 8;
#pragma unroll
        for (int li = 0; li < 8; ++li) {
#pragma unroll
            for (int ph = 0; ph < 2; ++ph)
                ur[li][ph] = *reinterpret_cast<const ushort8_t*>(
                    ubase + ((size_t)li * P + ph * 8) * V);
        }
    }
    __syncthreads();

    // phase 1: dot with v; 3-shfl reduce over vg8 -> bl[p][l]
#pragma unroll
    for (int li = 0; li < 8; ++li) {
        const int l = l0 + li;
        const float4 va = *reinterpret_cast<const float4*>(&vsh[l][vg8 * 8]);
        const float4 vb = *reinterpret_cast<const float4*>(&vsh[l][vg8 * 8 + 4]);
#pragma unroll
        for (int ph = 0; ph < 2; ++ph) {
            float d;
            d = bf2f(ur[li][ph][0]) * va.x;
            d = fmaf(bf2f(ur[li][ph][1]), va.y, d);
            d = fmaf(bf2f(ur[li][ph][2]), va.z, d);
            d = fmaf(bf2f(ur[li][ph][3]), va.w, d);
            d = fmaf(bf2f(ur[li][ph][4]), vb.x, d);
            d = fmaf(bf2f(ur[li][ph][5]), vb.y, d);
            d = fmaf(bf2f(ur[li][ph][6]), vb.z, d);
            d = fmaf(bf2f(ur[li][ph][7]), vb.w, d);
            d += __shfl_xor(d, 1, 64);
            d += __shfl_xor(d, 2, 64);
            d += __shfl_xor(d, 4, 64);
            if (vg8 == 0) bl[ph * 8 + pl8][l] = d;
        }
    }
    __syncthreads();

    // phase 2: each wave softmaxes 2 p's (lane = l); c overwrites bl
    float tloc = 0.f;
#pragma unroll
    for (int pi = 0; pi < 2; ++pi) {
        const int pli = w * 2 + pi;
        const int p = p0 + pli;
        float bv = bl[pli][lane];
        float* bp = bbuf + ((size_t)b * P + p) * L;
        if (add_prev) bv += bp[lane];
        bp[lane] = bv;
        float m = wmax64(bv);
        float e = __expf(bv - m);
        float ssum = wsum64(e);
        float cc = e / ssum;
        bl[pli][lane] = cc;
        if (do_T) tloc += cc * __logf(64.0f * (cc + 1e-12f));
    }
    if (do_T) {
        float dsum = wsum64(tloc);
        if (lane == 0) twv[w] = dsum;
    }
    __syncthreads();
    if (do_T && t == 0) {
        float s8 = twv[0] + twv[1] + twv[2] + twv[3] +
                   twv[4] + twv[5] + twv[6] + twv[7];
        atomicAdd(Tsum, s8 * (1.0f / LN64));
    }

    // phase 3: s-partial from registers; butterfly over pl8 (lane bits 3..5)
    float* spb = sp + (size_t)(b * NCH_BC + ch) * L * V;
#pragma unroll
    for (int li = 0; li < 8; ++li) {
        const int l = l0 + li;
        const float cA = bl[pl8][l];        // p = p0 + pl8
        const float cB = bl[8 + pl8][l];    // p = p0 + 8 + pl8
        float4 pa, pb;
        pa.x = cA * bf2f(ur[li][0][0]) + cB * bf2f(ur[li][1][0]);
        pa.y = cA * bf2f(ur[li][0][1]) + cB * bf2f(ur[li][1][1]);
        pa.z = cA * bf2f(ur[li][0][2]) + cB * bf2f(ur[li][1][2]);
        pa.w = cA * bf2f(ur[li][0][3]) + cB * bf2f(ur[li][1][3]);
        pb.x = cA * bf2f(ur[li][0][4]) + cB * bf2f(ur[li][1][4]);
        pb.y = cA * bf2f(ur[li][0][5]) + cB * bf2f(ur[li][1][5]);
        pb.z = cA * bf2f(ur[li][0][6]) + cB * bf2f(ur[li][1][6]);
        pb.w = cA * bf2f(ur[li][0][7]) + cB * bf2f(ur[li][1][7]);
#pragma unroll
        for (int m = 8; m <= 32; m <<= 1) {
            pa.x += __shfl_xor(pa.x, m, 64);
            pa.y += __shfl_xor(pa.y, m, 64);
            pa.z += __shfl_xor(pa.z, m, 64);
            pa.w += __shfl_xor(pa.w, m, 64);
            pb.x += __shfl_xor(pb.x, m, 64);
            pb.y += __shfl_xor(pb.y, m, 64);
            pb.z += __shfl_xor(pb.z, m, 64);
            pb.w += __shfl_xor(pb.w, m, 64);
        }
        if (pl8 == 0) {
            *reinterpret_cast<float4*>(spb + (size_t)l * V + vg8 * 8) = pa;
            *reinterpret_cast<float4*>(spb + (size_t)l * V + vg8 * 8 + 4) = pb;
        }
    }
}

// ---------------------------------------------------------------------------
// K_v: chunk-reduce + squash. sp[b][ch][l][v]. grid (L/4, B); wave w -> l.
// ---------------------------------------------------------------------------
__global__ __launch_bounds__(256) void k_v(const float* __restrict__ sp,
                                           float* __restrict__ vout,
                                           float* __restrict__ norms) {
    const int b = blockIdx.y;
    const int w = threadIdx.x >> 6, lane = threadIdx.x & 63;
    const int l = blockIdx.x * 4 + w;
    const float* p = sp + ((size_t)b * NCH_BC * L + l) * V + lane;
    float s = 0.f;
#pragma unroll 8
    for (int ch = 0; ch < NCH_BC; ++ch) s += p[(size_t)ch * L * V];
    float sq = wsum64(s * s);
    float f = sqrtf(sq) / (1.0f + sq);
    vout[((size_t)b * L + l) * V + lane] = s * f;
    if (norms && lane == 0) norms[b * L + l] = sq / (1.0f + sq);
}

// ---------------------------------------------------------------------------
// K_final: T and D. One block, 64 threads (lane = l).
// ---------------------------------------------------------------------------
__global__ void k_final(const float* __restrict__ Tsum,
                        const float* __restrict__ norms,
                        float* __restrict__ out) {
    const int lane = threadIdx.x & 63;
    float n[B];
    float sum = 0.f;
#pragma unroll
    for (int b = 0; b < B; ++b) { n[b] = norms[b * L + lane]; sum += n[b]; }
    const float mean = sum * (1.0f / B);
    float var = 0.f;
#pragma unroll
    for (int b = 0; b < B; ++b) { float d = n[b] - mean; var = fmaf(d, d, var); }
    var *= (1.0f / B);
    float sd = sqrtf(var);
    float D = wmax64(sd);
    if (lane == 0) {
        out[B * L * V] = Tsum[0] * (1.0f / (B * P));
        out[B * L * V + 1] = D;
    }
}

extern "C" void kernel_launch(void* const* d_in, const int* in_sizes, int n_in,
                              void* d_out, int out_size, void* d_ws, size_t ws_size,
                              hipStream_t stream) {
    const float* x = (const float*)d_in[0];   // (B,P,Q)
    const float* W = (const float*)d_in[1];   // (L,P,V,Q)
    float* out = (float*)d_out;               // v (B,L,V) then T, D

    char* ws = (char*)d_ws;
    ushort* uhat = (ushort*)ws;                        // [b][l][p][v] bf16 = 128 MB
    size_t off = (size_t)B * L * P * V * 2;
    float* spbuf = (float*)(ws + off); off += (size_t)B * NCH_BC * L * V * 4;  // 16 MB
    float* vbuf  = (float*)(ws + off); off += (size_t)B * L * V * 4;
    float* bbuf  = (float*)(ws + off); off += (size_t)B * P * L * 4;           // 4 MB [b][p][l]
    float* norms = (float*)(ws + off); off += (size_t)B * L * 4;
    float* Tsum  = (float*)(ws + off); off += 256;

    hipMemsetAsync(Tsum, 0, sizeof(float), stream);

    // u_hat
    hipLaunchKernelGGL(k_uhat, dim3(2048), dim3(256), 0, stream, W, x, uhat);
    // iter 0: uniform c -> v0
    hipLaunchKernelGGL(k_s, dim3(L, B), dim3(256), 0, stream, uhat, vbuf);
    // b1 = v0.u ; c1 ; partial s1 (fused, u in registers)
    hipLaunchKernelGGL(k_bc, dim3(NCH_BC, B), dim3(512), 0, stream,
                       uhat, vbuf, bbuf, spbuf, Tsum, 0, 0);
    // v1
    hipLaunchKernelGGL(k_v, dim3(L / 4, B), dim3(256), 0, stream,
                       spbuf, vbuf, (float*)nullptr);
    // b2 = b1 + v1.u ; c2 ; T partials ; partial s2
    hipLaunchKernelGGL(k_bc, dim3(NCH_BC, B), dim3(512), 0, stream,
                       uhat, vbuf, bbuf, spbuf, Tsum, 1, 1);
    // v2 -> out, norms
    hipLaunchKernelGGL(k_v, dim3(L / 4, B), dim3(256), 0, stream,
                       spbuf, out, norms);
    hipLaunchKernelGGL(k_final, dim3(1), dim3(64), 0, stream, Tsum, norms, out);
}